// Round 6
// baseline (1038.458 us; speedup 1.0000x reference)
//
#include <hip/hip_runtime.h>
#include <hip/hip_bf16.h>
#include <math.h>

// SNN forward: 64 -> 1024 -> 1024 -> 10, T=4000, B=16, LIF beta=exp(-0.025),
// thr=1, hard reset to 0, Dale clamp W>=0.
// Layer-phased: per time-chunk, GEMM (spikes @ W bf16-limbs, fp32 acc) ->
// LIF scan (fp64 membranes). Spikes as bf16 {0,1}.
// R5 postmortem: scan_hidden was 1 wave/CU with a collapsed register
// pipeline -> ported the proven scan_out LDS-dbuf staging structure to it.
// GEMM XCD swizzle flipped to n-major: per XCD, all B panels (4 MB) stay
// L2-resident and each A m-tile is reused 8x from L2.

#define T_STEPS 4000
#define NB 16
#define N_IN 64
#define NH 1024
#define N_OUT 10
#define SEGO 40           // scan_out segment rows; 2 x 40 KB LDS
#define SEGH 50           // scan_hidden segment rows; 2 x 12.8 KB LDS

typedef __attribute__((ext_vector_type(8))) short bf16x8;
typedef __attribute__((ext_vector_type(4))) float f32x4;
typedef __hip_bfloat16 bf16;

#define ASG(p) (const __attribute__((address_space(1))) void*)(p)
#define ASL(p) (__attribute__((address_space(3))) void*)(p)

// ---------------- small utility kernels ----------------

__global__ void k_zero(double* p, int n) {
    int i = blockIdx.x * 256 + threadIdx.x;
    if (i < n) p[i] = 0.0;
}

__global__ void k_cvt(const float* __restrict__ in, bf16* __restrict__ out, int n) {
    int i = blockIdx.x * 256 + threadIdx.x;
    if (i < n) out[i] = __float2bfloat16(in[i]);   // 0.0/1.0 -> exact
}

// Build BT[n][k2] (row-major [Npad x 2K]) from W [K x N] row-major.
// Limb-interleaved K2: k2 -> kt2 = k2>>6, kk = k2&63; limb = kt2&1,
// source k = (kt2>>1)*64 + kk. limb0 = hi(max(W,0)), limb1 = w - hi.
__global__ void k_limbs(const float* __restrict__ W, bf16* __restrict__ BT,
                        int K, int N, int Npad) {
    int idx = blockIdx.x * 256 + threadIdx.x;
    int total = Npad * 2 * K;
    if (idx >= total) return;
    int n  = idx / (2 * K);
    int k2 = idx - n * (2 * K);
    int kt2 = k2 >> 6;
    int kk  = k2 & 63;
    int k   = ((kt2 >> 1) << 6) + kk;
    float v = 0.f;
    if (n < N) {
        float w = fmaxf(W[(size_t)k * N + n], 0.f);      // Dale's law clamp
        float hi = __bfloat162float(__float2bfloat16(w));
        v = ((kt2 & 1) == 0) ? w : (w - hi);
    }
    BT[idx] = __float2bfloat16(v);
}

// ---------------- GEMM: C[M x ldc] = A[M x KA] @ BT^T, bf16 in, f32 out ----
// BT is [Npad x K2], limb-interleaved: k-iteration kt uses A k-tile (kt>>1).
// 128x128 tile, BK=64, 4 waves (2x2), 4x4 16x16x32 frags per wave.
// 1D grid, bijective XCD swizzle (m204), n-major block order within XCD:
// B panels stay L2-resident per XCD, A m-tiles reused gy x from L2.

__global__ __launch_bounds__(256) void k_gemm(
    const bf16* __restrict__ A, const bf16* __restrict__ BT,
    float* __restrict__ C, int KA, int K2, int ldc, int gx) {
    const int nwg = gridDim.x;
    const int wg  = blockIdx.x;
    const int q = nwg >> 3, r = nwg & 7;
    const int xcd = wg & 7, idx0 = wg >> 3;
    const int swz = (xcd < r ? xcd * (q + 1) : r * (q + 1) + (xcd - r) * q) + idx0;
    const int gy = nwg / gx;
    const int n0 = (swz % gy) * 128;      // n-major within XCD chunk
    const int m0 = (swz / gy) * 128;
    __shared__ __align__(16) short Alds[128 * 64];
    __shared__ __align__(16) short Blds[128 * 64];
    const int tid  = threadIdx.x;
    const int lane = tid & 63;
    const int wave = tid >> 6;
    const int wbase = wave * 64;          // lane-uniform within wave
    const int wm = (wave >> 1) * 64;
    const int wn = (wave & 1) * 64;
    const int r16 = lane & 15;
    const int kg  = lane >> 4;
    f32x4 acc[4][4] = {};
    const int nkt = K2 >> 6;
    for (int kt = 0; kt < nkt; ++kt) {
        const int kB0 = kt << 6;
        const int kA0 = (kt >> 1) << 6;
        __syncthreads();
        // stage tiles: 1024 x 16B each; global_load_lds, 16B/lane
#pragma unroll
        for (int rr = 0; rr < 4; ++rr) {
            int idx = rr * 256 + wbase + lane;   // 16B unit within tile
            int row = idx >> 3;
            int c8  = (idx & 7) << 3;
            if ((kt & 1) == 0)
                __builtin_amdgcn_global_load_lds(
                    ASG(&A[(size_t)(m0 + row) * KA + kA0 + c8]),
                    ASL(&Alds[(rr * 256 + wbase) * 8]), 16, 0, 0);
            __builtin_amdgcn_global_load_lds(
                ASG(&BT[(size_t)(n0 + row) * K2 + kB0 + c8]),
                ASL(&Blds[(rr * 256 + wbase) * 8]), 16, 0, 0);
        }
        __syncthreads();
#pragma unroll
        for (int kk = 0; kk < 2; ++kk) {
            bf16x8 af[4], bfr[4];
#pragma unroll
            for (int i = 0; i < 4; ++i) {
                af[i]  = *(const bf16x8*)&Alds[(wm + i * 16 + r16) * 64 + kk * 32 + kg * 8];
                bfr[i] = *(const bf16x8*)&Blds[(wn + i * 16 + r16) * 64 + kk * 32 + kg * 8];
            }
#pragma unroll
            for (int mi = 0; mi < 4; ++mi)
#pragma unroll
                for (int ni = 0; ni < 4; ++ni)
                    acc[mi][ni] = __builtin_amdgcn_mfma_f32_16x16x32_bf16(
                        af[mi], bfr[ni], acc[mi][ni], 0, 0, 0);
        }
    }
    // epilogue: D row = kg*4 + r, col = r16 (m89 mapping); store cols < ldc
#pragma unroll
    for (int mi = 0; mi < 4; ++mi)
#pragma unroll
        for (int ni = 0; ni < 4; ++ni) {
            int col = n0 + wn + ni * 16 + r16;
            if (col < ldc) {
#pragma unroll
                for (int rr = 0; rr < 4; ++rr) {
                    int row = m0 + wm + mi * 16 + kg * 4 + rr;
                    C[(size_t)row * ldc + col] = acc[mi][ni][rr];
                }
            }
        }
}

// ---------------- LIF scan kernels (fp64 membranes) ----------------

// hidden layer: 16384 chains, 64-thread blocks (1 wave) x 256 blocks.
// Block owns 64 contiguous columns; stages SEGH t-rows of its columns into
// statically-distinct segA/segB via global_load_lds (4B/lane), x2-unrolled
// segment loop, 10-step unrolled processing with batched LDS reads/stores.
__global__ __launch_bounds__(64) void k_scan_hidden(
    const float* __restrict__ I, const float* __restrict__ bias,
    double* __restrict__ mstate, bf16* __restrict__ S, int Tc, double beta) {
    __shared__ __align__(16) float segA[SEGH * 64];
    __shared__ __align__(16) float segB[SEGH * 64];
    const int lane = threadIdx.x;
    const int gid  = blockIdx.x * 64 + lane;
    const int j = gid & (NH - 1);
    double m = mstate[gid];
    const float bj = bias[j];
    const size_t stride = (size_t)NB * NH;       // 16384, per-t stride
    const int nseg = Tc / SEGH;                  // even by host (Tc % 100 == 0)

#define H_PREFETCH(SEGBUF, SIDX)                                            \
    {                                                                       \
        const float* src = I + (size_t)(SIDX) * SEGH * stride + gid;        \
        _Pragma("unroll")                                                   \
        for (int rr = 0; rr < SEGH; ++rr)                                   \
            __builtin_amdgcn_global_load_lds(                               \
                ASG(src + (size_t)rr * stride),                             \
                ASL(&SEGBUF[rr * 64]), 4, 0, 0);                            \
    }

#define H_PROC(SEGBUF, SIDX)                                                \
    {                                                                       \
        const int btt = (SIDX) * SEGH;                                      \
        _Pragma("unroll")                                                   \
        for (int sb = 0; sb < SEGH / 10; ++sb) {                            \
            float v[10];                                                    \
            _Pragma("unroll")                                               \
            for (int u = 0; u < 10; ++u)                                    \
                v[u] = SEGBUF[(sb * 10 + u) * 64 + lane];                   \
            unsigned short o[10];                                           \
            _Pragma("unroll")                                               \
            for (int u = 0; u < 10; ++u) {                                  \
                m = beta * m + (double)(v[u] + bj);                         \
                bool sp = (m >= 1.0);                                       \
                o[u] = sp ? (unsigned short)0x3F80 : (unsigned short)0;     \
                m = sp ? 0.0 : m;                                           \
            }                                                               \
            _Pragma("unroll")                                               \
            for (int u = 0; u < 10; ++u)                                    \
                ((unsigned short*)S)[(size_t)(btt + sb * 10 + u) * stride + gid] = o[u]; \
        }                                                                   \
    }

    H_PREFETCH(segA, 0);
    for (int s = 0; s < nseg; s += 2) {
        asm volatile("s_waitcnt vmcnt(0)" ::: "memory");   // segA resident
        __builtin_amdgcn_sched_barrier(0);
        H_PREFETCH(segB, s + 1);
        __builtin_amdgcn_sched_barrier(0);
        H_PROC(segA, s);
        asm volatile("s_waitcnt vmcnt(0)" ::: "memory");   // segB resident
        __builtin_amdgcn_sched_barrier(0);
        if (s + 2 < nseg) H_PREFETCH(segA, s + 2);
        __builtin_amdgcn_sched_barrier(0);
        H_PROC(segB, s + 1);
    }
    mstate[gid] = m;
#undef H_PREFETCH
#undef H_PROC
}

// output layer: 256 chains (160 live), compact I2 [Tc x 256].
__global__ __launch_bounds__(256) void k_scan_out(
    const float* __restrict__ I2, const float* __restrict__ bias,
    double* __restrict__ mstate, float* __restrict__ out,
    int Tc, int t0, double beta) {
    __shared__ __align__(16) float segA[SEGO * 256];
    __shared__ __align__(16) float segB[SEGO * 256];
    const int tid  = threadIdx.x;
    const int lane = tid & 63;
    const int wave = tid >> 6;
    const int k = tid & 15;
    const int b = tid >> 4;
    double m = mstate[tid];
    float bj = (k < N_OUT) ? bias[k] : 0.f;
    const int nseg = Tc / SEGO;                  // even by host

#define O_PREFETCH(SEGBUF, SIDX)                                            \
    {                                                                       \
        const float* src = I2 + (size_t)(SIDX) * SEGO * 256 + wave * 64 + lane; \
        _Pragma("unroll 8")                                                 \
        for (int rr = 0; rr < SEGO; ++rr)                                   \
            __builtin_amdgcn_global_load_lds(                               \
                ASG(src + (size_t)rr * 256),                                \
                ASL(&SEGBUF[rr * 256 + wave * 64]), 4, 0, 0);               \
    }

#define O_PROC(SEGBUF, SIDX)                                                \
    {                                                                       \
        const int btt = (SIDX) * SEGO;                                      \
        _Pragma("unroll")                                                   \
        for (int sb = 0; sb < SEGO / 8; ++sb) {                             \
            float v[8];                                                     \
            _Pragma("unroll")                                               \
            for (int u = 0; u < 8; ++u)                                     \
                v[u] = SEGBUF[(sb * 8 + u) * 256 + tid];                    \
            float o[8];                                                     \
            _Pragma("unroll")                                               \
            for (int u = 0; u < 8; ++u) {                                   \
                m = beta * m + (double)(v[u] + bj);                         \
                bool sp = (m >= 1.0);                                       \
                o[u] = sp ? 1.f : 0.f;                                      \
                m = sp ? 0.0 : m;                                           \
            }                                                               \
            if (k < N_OUT) {                                                \
                _Pragma("unroll")                                           \
                for (int u = 0; u < 8; ++u)                                 \
                    out[((size_t)(t0 + btt + sb * 8 + u) * NB + b) * N_OUT + k] = o[u]; \
            }                                                               \
        }                                                                   \
    }

    O_PREFETCH(segA, 0);
    for (int s = 0; s < nseg; s += 2) {
        asm volatile("s_waitcnt vmcnt(0)" ::: "memory");   // segA resident
        __builtin_amdgcn_sched_barrier(0);
        O_PREFETCH(segB, s + 1);
        __builtin_amdgcn_sched_barrier(0);
        O_PROC(segA, s);
        asm volatile("s_waitcnt vmcnt(0)" ::: "memory");   // segB resident
        __builtin_amdgcn_sched_barrier(0);
        if (s + 2 < nseg) O_PREFETCH(segA, s + 2);
        __builtin_amdgcn_sched_barrier(0);
        O_PROC(segB, s + 1);
    }
    mstate[tid] = m;
#undef O_PREFETCH
#undef O_PROC
}

// ---------------- host ----------------

extern "C" void kernel_launch(void* const* d_in, const int* in_sizes, int n_in,
                              void* d_out, int out_size, void* d_ws, size_t ws_size,
                              hipStream_t stream) {
    const float* in_sp = (const float*)d_in[0];
    const float* W0 = (const float*)d_in[1];
    const float* b0 = (const float*)d_in[2];
    const float* W1 = (const float*)d_in[3];
    const float* b1 = (const float*)d_in[4];
    const float* W2 = (const float*)d_in[5];
    const float* b2 = (const float*)d_in[6];
    float* out = (float*)d_out;

    char* p = (char*)d_ws;
    auto carve = [&](size_t bytes) -> void* {
        char* r = p; p += (bytes + 255) & ~(size_t)255; return (void*)r;
    };
    bf16* A_in = (bf16*)carve((size_t)T_STEPS * NB * N_IN * 2);
    bf16* BT0  = (bf16*)carve((size_t)NH * 2 * N_IN * 2);
    bf16* BT1  = (bf16*)carve((size_t)NH * 2 * NH * 2);
    bf16* BT2  = (bf16*)carve((size_t)128 * 2 * NH * 2);
    double* m0s = (double*)carve((size_t)NB * NH * 8);
    double* m1s = (double*)carve((size_t)NB * NH * 8);
    double* m2s = (double*)carve((size_t)NB * 16 * 8);
    size_t fixed = (size_t)(p - (char*)d_ws);

    // Tc | 4000, Tc % 400 == 0 (scan_out 2x40, scan_hidden 2x50), Mc % 128 == 0
    const int tc_opts[3] = {2000, 800, 400};
    int Tc = 400;
    for (int i = 0; i < 3; ++i) {
        size_t Mc_ = (size_t)tc_opts[i] * NB;
        size_t need = fixed
            + ((Mc_ * NH * 4 + 255) & ~(size_t)255)
            + ((Mc_ * 16 * 4 + 255) & ~(size_t)255)
            + ((Mc_ * NH * 2 + 255) & ~(size_t)255);
        if (need <= ws_size) { Tc = tc_opts[i]; break; }
    }
    size_t Mc = (size_t)Tc * NB;
    float* IBUF  = (float*)carve(Mc * NH * 4);
    float* I2BUF = (float*)carve(Mc * 16 * 4);
    bf16*  S     = (bf16*)carve(Mc * NH * 2);

    const double beta = exp(-0.25 / 10.0);

    int nM = NB * NH;
    k_zero<<<(nM + 255) / 256, 256, 0, stream>>>(m0s, nM);
    k_zero<<<(nM + 255) / 256, 256, 0, stream>>>(m1s, nM);
    k_zero<<<1, 256, 0, stream>>>(m2s, NB * 16);

    int nIn = T_STEPS * NB * N_IN;
    k_cvt<<<(nIn + 255) / 256, 256, 0, stream>>>(in_sp, A_in, nIn);

    k_limbs<<<(NH * 2 * N_IN + 255) / 256, 256, 0, stream>>>(W0, BT0, N_IN, NH, NH);
    k_limbs<<<(NH * 2 * NH + 255) / 256, 256, 0, stream>>>(W1, BT1, NH, NH, NH);
    k_limbs<<<(128 * 2 * NH + 255) / 256, 256, 0, stream>>>(W2, BT2, NH, N_OUT, 128);

    const int C = T_STEPS / Tc;
    const int gx = (int)(Mc / 128);
    for (int c = 0; c < C; ++c) {
        int t0 = c * Tc;
        const bf16* Ain_c = A_in + (size_t)t0 * NB * N_IN;
        // layer 0
        k_gemm<<<gx * 8, 256, 0, stream>>>(Ain_c, BT0, IBUF, N_IN, 2 * N_IN, NH, gx);
        k_scan_hidden<<<(NB * NH) / 64, 64, 0, stream>>>(IBUF, b0, m0s, S, Tc, beta);
        // layer 1
        k_gemm<<<gx * 8, 256, 0, stream>>>(S, BT1, IBUF, NH, 2 * NH, NH, gx);
        k_scan_hidden<<<(NB * NH) / 64, 64, 0, stream>>>(IBUF, b1, m1s, S, Tc, beta);
        // layer 2 (compact 16-col C)
        k_gemm<<<gx, 256, 0, stream>>>(S, BT2, I2BUF, NH, 2 * NH, 16, gx);
        k_scan_out<<<1, 256, 0, stream>>>(I2BUF, b2, m2s, out, Tc, t0, beta);
    }
}

// Round 8
// 984.675 us; speedup vs baseline: 1.0546x; 1.0546x over previous
//
#include <hip/hip_runtime.h>
#include <hip/hip_bf16.h>
#include <math.h>

// SNN forward: 64 -> 1024 -> 1024 -> 10, T=4000, B=16, LIF beta=exp(-0.025),
// thr=1, hard reset to 0, Dale clamp W>=0.
// Layer-phased: per time-chunk, GEMM (spikes @ W bf16-limbs, fp32 acc) ->
// LIF scan (fp64 membranes). Spikes as bf16 {0,1}.
// R8: fixed k_gemm8 WAR race (R7): stages may only target regions whose
// reads have drained past a barrier. A-half reads finish at P2 -> A staged
// at P3; B-half reads finish at P1 -> B staged at P2. vmcnt(8) per KTILE
// (each KTILE issues 8 global_load_lds/wave).

#define T_STEPS 4000
#define NB 16
#define N_IN 64
#define NH 1024
#define N_OUT 10
#define SEGO 40           // scan_out segment rows; 2 x 40 KB LDS
#define SEGH 50           // scan_hidden segment rows; 2 x 12.8 KB LDS

typedef __attribute__((ext_vector_type(8))) short bf16x8;
typedef __attribute__((ext_vector_type(4))) float f32x4;
typedef __hip_bfloat16 bf16;

#define ASG(p) (const __attribute__((address_space(1))) void*)(p)
#define ASL(p) (__attribute__((address_space(3))) void*)(p)

// ---------------- small utility kernels ----------------

__global__ void k_zero(double* p, int n) {
    int i = blockIdx.x * 256 + threadIdx.x;
    if (i < n) p[i] = 0.0;
}

__global__ void k_cvt(const float* __restrict__ in, bf16* __restrict__ out, int n) {
    int i = blockIdx.x * 256 + threadIdx.x;
    if (i < n) out[i] = __float2bfloat16(in[i]);   // 0.0/1.0 -> exact
}

// Build BT[n][k2] (row-major [Npad x 2K]) from W [K x N] row-major.
// interleave=1: [hi64|lo64] alternating per source 64-block (for k_gemm's
//               A-tile-reuse addressing).
// interleave=0: plain [hi(0..K) | lo(0..K)] (for k_gemm8; A col = k2 & (K-1)).
__global__ void k_limbs(const float* __restrict__ W, bf16* __restrict__ BT,
                        int K, int N, int Npad, int interleave) {
    int idx = blockIdx.x * 256 + threadIdx.x;
    int total = Npad * 2 * K;
    if (idx >= total) return;
    int n  = idx / (2 * K);
    int k2 = idx - n * (2 * K);
    int k, lo;
    if (interleave) {
        int kt2 = k2 >> 6, kk = k2 & 63;
        k = ((kt2 >> 1) << 6) + kk;
        lo = kt2 & 1;
    } else {
        lo = (k2 >= K);
        k = lo ? (k2 - K) : k2;
    }
    float v = 0.f;
    if (n < N) {
        float w = fmaxf(W[(size_t)k * N + n], 0.f);      // Dale's law clamp
        float hi = __bfloat162float(__float2bfloat16(w));
        v = lo ? (w - hi) : w;
    }
    BT[idx] = __float2bfloat16(v);
}

// ---------------- 128^2 2-phase GEMM (layers 0 and 2) ----------------
// BT interleaved: k-iteration kt uses A k-tile (kt>>1).

__global__ __launch_bounds__(256) void k_gemm(
    const bf16* __restrict__ A, const bf16* __restrict__ BT,
    float* __restrict__ C, int KA, int K2, int ldc, int gx) {
    const int nwg = gridDim.x;
    const int wg  = blockIdx.x;
    const int q = nwg >> 3, r = nwg & 7;
    const int xcd = wg & 7, idx0 = wg >> 3;
    const int swz = (xcd < r ? xcd * (q + 1) : r * (q + 1) + (xcd - r) * q) + idx0;
    const int gy = nwg / gx;
    const int n0 = (swz % gy) * 128;      // n-major within XCD chunk
    const int m0 = (swz / gy) * 128;
    __shared__ __align__(16) short Alds[128 * 64];
    __shared__ __align__(16) short Blds[128 * 64];
    const int tid  = threadIdx.x;
    const int lane = tid & 63;
    const int wave = tid >> 6;
    const int wbase = wave * 64;
    const int wm = (wave >> 1) * 64;
    const int wn = (wave & 1) * 64;
    const int r16 = lane & 15;
    const int kg  = lane >> 4;
    f32x4 acc[4][4] = {};
    const int nkt = K2 >> 6;
    for (int kt = 0; kt < nkt; ++kt) {
        const int kB0 = kt << 6;
        const int kA0 = (kt >> 1) << 6;
        __syncthreads();
#pragma unroll
        for (int rr = 0; rr < 4; ++rr) {
            int idx = rr * 256 + wbase + lane;
            int row = idx >> 3;
            int c8  = (idx & 7) << 3;
            if ((kt & 1) == 0)
                __builtin_amdgcn_global_load_lds(
                    ASG(&A[(size_t)(m0 + row) * KA + ((kA0 + c8) & (KA - 1))]),
                    ASL(&Alds[(rr * 256 + wbase) * 8]), 16, 0, 0);
            __builtin_amdgcn_global_load_lds(
                ASG(&BT[(size_t)(n0 + row) * K2 + kB0 + c8]),
                ASL(&Blds[(rr * 256 + wbase) * 8]), 16, 0, 0);
        }
        __syncthreads();
#pragma unroll
        for (int kk = 0; kk < 2; ++kk) {
            bf16x8 af[4], bfr[4];
#pragma unroll
            for (int i = 0; i < 4; ++i) {
                af[i]  = *(const bf16x8*)&Alds[(wm + i * 16 + r16) * 64 + kk * 32 + kg * 8];
                bfr[i] = *(const bf16x8*)&Blds[(wn + i * 16 + r16) * 64 + kk * 32 + kg * 8];
            }
#pragma unroll
            for (int mi = 0; mi < 4; ++mi)
#pragma unroll
                for (int ni = 0; ni < 4; ++ni)
                    acc[mi][ni] = __builtin_amdgcn_mfma_f32_16x16x32_bf16(
                        af[mi], bfr[ni], acc[mi][ni], 0, 0, 0);
        }
    }
#pragma unroll
    for (int mi = 0; mi < 4; ++mi)
#pragma unroll
        for (int ni = 0; ni < 4; ++ni) {
            int col = n0 + wn + ni * 16 + r16;
            if (col < ldc) {
#pragma unroll
                for (int rr = 0; rr < 4; ++rr) {
                    int row = m0 + wm + mi * 16 + kg * 4 + rr;
                    C[(size_t)row * ldc + col] = acc[mi][ni][rr];
                }
            }
        }
}

// ---------------- 256^2 8-phase GEMM (layer 1) ----------------
// Fixed shape: KA=1024, K2=2048, N=1024, ldc=1024. M multiple of 256.
// BT plain [hi|lo]; A col = k & 1023.
// LDS: 2 buf x {A,B} x 2 half-tiles x 16KB = 128 KB. Half-tile = 128x64 bf16,
// subtiled 16x32 (1024B), st_16x32 swizzle: byte ^= ((byte>>9)&1)<<5.
// Staging: linear LDS dest + pre-swizzled global source (rule #21).
// Stage ordering invariant (R8): a region is staged only in a phase after all
// ds_reads of it have drained past a barrier (A at P3, B at P2).

__global__ __launch_bounds__(512) void k_gemm8(
    const bf16* __restrict__ A, const bf16* __restrict__ BT,
    float* __restrict__ C, int gx) {
    const int KA = 1024, K2 = 2048;
    const int kmask = KA - 1;
    const int nwg = gridDim.x;
    const int wg  = blockIdx.x;
    const int q = nwg >> 3, r = nwg & 7;
    const int xcd = wg & 7, idx0 = wg >> 3;
    const int swz = (xcd < r ? xcd * (q + 1) : r * (q + 1) + (xcd - r) * q) + idx0;
    const int gy = nwg / gx;              // 4
    const int n0 = (swz % gy) * 256;      // n-major within XCD chunk
    const int m0 = (swz / gy) * 256;

    __shared__ __align__(16) char LDS[131072];
    const int tid  = threadIdx.x;
    const int lane = tid & 63;
    const int wave = tid >> 6;
    const int wm = (wave >> 2) * 128;     // 0 / 128
    const int wn = (wave & 3) * 64;       // 0..192
    const int r16l = lane & 15;
    const int kg   = lane >> 4;
    const int hA   = wave >> 2;           // A half this wave reads
    const int hB   = (wave & 3) >> 1;     // B half this wave reads
    const int wn64 = wave & 1;            // 64-col sub-block within B half

    // per-lane swizzled fragment-read offset within a half-tile
    const int po = (r16l * 64 + kg * 16) ^ (((r16l >> 3) & 1) << 5);
    const char* bA[2] = { LDS + hA * 16384 + po,
                          LDS + 65536 + hA * 16384 + po };
    const char* bB[2] = { LDS + 32768 + hB * 16384 + po,
                          LDS + 98304 + hB * 16384 + po };
    const int bOff = wn64 * 8192;

    // staging: per-thread pre-swizzled (row, col) for the 2 rounds
    int s_row[2], s_col[2];
#pragma unroll
    for (int rr = 0; rr < 2; ++rr) {
        int d = (rr * 512 + tid) * 16;            // linear LDS dest byte
        int l = d ^ (((d >> 9) & 1) << 5);        // logical element byte
        int sub = l >> 10;
        int w = l & 1023;
        s_row[rr] = (sub >> 1) * 16 + (w >> 6);
        s_col[rr] = ((sub & 1) * 64 + (w & 63)) >> 1;
    }

#define HBASE(BUF, OP, HALF) ((((BUF) * 2 + (OP)) * 2 + (HALF)) * 16384)
#define STAGE_A(BUF, HALF, K0)                                              \
    {                                                                       \
        _Pragma("unroll")                                                   \
        for (int rr = 0; rr < 2; ++rr)                                      \
            __builtin_amdgcn_global_load_lds(                               \
                ASG(A + (size_t)(m0 + (HALF) * 128 + s_row[rr]) * KA        \
                    + (((K0) + s_col[rr]) & kmask)),                        \
                ASL(LDS + HBASE(BUF, 0, HALF) + (rr * 512 + wave * 64) * 16), \
                16, 0, 0);                                                  \
    }
#define STAGE_B(BUF, HALF, K0)                                              \
    {                                                                       \
        _Pragma("unroll")                                                   \
        for (int rr = 0; rr < 2; ++rr)                                      \
            __builtin_amdgcn_global_load_lds(                               \
                ASG(BT + (size_t)(n0 + (HALF) * 128 + s_row[rr]) * K2       \
                    + (K0) + s_col[rr]),                                    \
                ASL(LDS + HBASE(BUF, 1, HALF) + (rr * 512 + wave * 64) * 16), \
                16, 0, 0);                                                  \
    }

    f32x4 acc[8][4] = {};
    bf16x8 a[4][2], b[4][2];

#define MM(MIB, NIB)                                                        \
    {                                                                       \
        _Pragma("unroll")                                                   \
        for (int i = 0; i < 4; ++i)                                         \
            _Pragma("unroll")                                               \
            for (int j = 0; j < 2; ++j) {                                   \
                acc[(MIB) + i][(NIB) + j] =                                 \
                    __builtin_amdgcn_mfma_f32_16x16x32_bf16(                \
                        a[i][0], b[(NIB) + j][0], acc[(MIB) + i][(NIB) + j], 0, 0, 0); \
                acc[(MIB) + i][(NIB) + j] =                                 \
                    __builtin_amdgcn_mfma_f32_16x16x32_bf16(                \
                        a[i][1], b[(NIB) + j][1], acc[(MIB) + i][(NIB) + j], 0, 0, 0); \
            }                                                               \
    }

#define PH_SYNC()                                                           \
    __builtin_amdgcn_s_barrier();                                           \
    asm volatile("s_waitcnt lgkmcnt(0)" ::: "memory");                      \
    __builtin_amdgcn_sched_barrier(0);

#define KTILE(BUF, SK)                                                      \
    {                                                                       \
        /* P0: ds a[0-3] (8) + b[0-1] (4); no stage */                      \
        _Pragma("unroll")                                                   \
        for (int i = 0; i < 4; ++i) {                                       \
            a[i][0] = *(const bf16x8*)(bA[BUF] + i * 2048);                 \
            a[i][1] = *(const bf16x8*)(bA[BUF] + i * 2048 + 1024);          \
        }                                                                   \
        _Pragma("unroll")                                                   \
        for (int j = 0; j < 2; ++j) {                                       \
            b[j][0] = *(const bf16x8*)(bB[BUF] + bOff + j * 2048);          \
            b[j][1] = *(const bf16x8*)(bB[BUF] + bOff + j * 2048 + 1024);   \
        }                                                                   \
        PH_SYNC();                                                          \
        __builtin_amdgcn_s_setprio(1);                                      \
        MM(0, 0);                                                           \
        __builtin_amdgcn_s_setprio(0);                                      \
        __builtin_amdgcn_s_barrier();                                       \
        /* P1: ds b[2-3] (4); no stage */                                   \
        _Pragma("unroll")                                                   \
        for (int j = 0; j < 2; ++j) {                                       \
            b[2 + j][0] = *(const bf16x8*)(bB[BUF] + bOff + (2 + j) * 2048); \
            b[2 + j][1] = *(const bf16x8*)(bB[BUF] + bOff + (2 + j) * 2048 + 1024); \
        }                                                                   \
        PH_SYNC();                                                          \
        __builtin_amdgcn_s_setprio(1);                                      \
        MM(0, 2);                                                           \
        __builtin_amdgcn_s_setprio(0);                                      \
        __builtin_amdgcn_s_barrier();                                       \
        /* P2: ds a[4-7] (8); stage B-h0+B-h1 (B reads drained at P1) */    \
        _Pragma("unroll")                                                   \
        for (int i = 0; i < 4; ++i) {                                       \
            a[i][0] = *(const bf16x8*)(bA[BUF] + (4 + i) * 2048);           \
            a[i][1] = *(const bf16x8*)(bA[BUF] + (4 + i) * 2048 + 1024);    \
        }                                                                   \
        STAGE_B(BUF, 0, SK);                                                \
        STAGE_B(BUF, 1, SK);                                                \
        PH_SYNC();                                                          \
        __builtin_amdgcn_s_setprio(1);                                      \
        MM(4, 0);                                                           \
        __builtin_amdgcn_s_setprio(0);                                      \
        __builtin_amdgcn_s_barrier();                                       \
        /* P3: stage A-h0+A-h1 (A reads drained at P2); vmcnt(8) */         \
        STAGE_A(BUF, 0, SK);                                                \
        STAGE_A(BUF, 1, SK);                                                \
        PH_SYNC();                                                          \
        __builtin_amdgcn_s_setprio(1);                                      \
        MM(4, 2);                                                           \
        __builtin_amdgcn_s_setprio(0);                                      \
        asm volatile("s_waitcnt vmcnt(8)" ::: "memory");                    \
        __builtin_amdgcn_sched_barrier(0);                                  \
        __builtin_amdgcn_s_barrier();                                       \
    }

    // prologue: stage tiles 0 (buf0) and 1 (buf1); wait tile0 collectively
    STAGE_A(0, 0, 0);  STAGE_A(0, 1, 0);  STAGE_B(0, 0, 0);  STAGE_B(0, 1, 0);
    STAGE_A(1, 0, 64); STAGE_A(1, 1, 64); STAGE_B(1, 0, 64); STAGE_B(1, 1, 64);
    asm volatile("s_waitcnt vmcnt(8)" ::: "memory");
    __builtin_amdgcn_sched_barrier(0);
    __builtin_amdgcn_s_barrier();

    for (int it = 0; it < 16; ++it) {
        const int k0  = it * 128;
        const int ksA = (k0 + 128) & (K2 - 1);   // buf0's next tile (wraps to dummy at tail)
        const int ksB = (k0 + 192) & (K2 - 1);   // buf1's next tile
        KTILE(0, ksA);
        KTILE(1, ksB);
    }
    asm volatile("s_waitcnt vmcnt(0)" ::: "memory");
    __builtin_amdgcn_sched_barrier(0);

    // epilogue: D row = kg*4 + rr, col = r16l
#pragma unroll
    for (int mi = 0; mi < 8; ++mi)
#pragma unroll
        for (int ni = 0; ni < 4; ++ni)
#pragma unroll
            for (int rr = 0; rr < 4; ++rr) {
                int row = m0 + wm + mi * 16 + kg * 4 + rr;
                int col = n0 + wn + ni * 16 + r16l;
                C[(size_t)row * 1024 + col] = acc[mi][ni][rr];
            }
#undef KTILE
#undef PH_SYNC
#undef MM
#undef STAGE_A
#undef STAGE_B
#undef HBASE
}

// ---------------- LIF scan kernels (fp64 membranes) ----------------

__global__ __launch_bounds__(64) void k_scan_hidden(
    const float* __restrict__ I, const float* __restrict__ bias,
    double* __restrict__ mstate, bf16* __restrict__ S, int Tc, double beta) {
    __shared__ __align__(16) float segA[SEGH * 64];
    __shared__ __align__(16) float segB[SEGH * 64];
    const int lane = threadIdx.x;
    const int gid  = blockIdx.x * 64 + lane;
    const int j = gid & (NH - 1);
    double m = mstate[gid];
    const float bj = bias[j];
    const size_t stride = (size_t)NB * NH;
    const int nseg = Tc / SEGH;

#define H_PREFETCH(SEGBUF, SIDX)                                            \
    {                                                                       \
        const float* src = I + (size_t)(SIDX) * SEGH * stride + gid;        \
        _Pragma("unroll")                                                   \
        for (int rr = 0; rr < SEGH; ++rr)                                   \
            __builtin_amdgcn_global_load_lds(                               \
                ASG(src + (size_t)rr * stride),                             \
                ASL(&SEGBUF[rr * 64]), 4, 0, 0);                            \
    }

#define H_PROC(SEGBUF, SIDX)                                                \
    {                                                                       \
        const int btt = (SIDX) * SEGH;                                      \
        _Pragma("unroll")                                                   \
        for (int sb = 0; sb < SEGH / 10; ++sb) {                            \
            float v[10];                                                    \
            _Pragma("unroll")                                               \
            for (int u = 0; u < 10; ++u)                                    \
                v[u] = SEGBUF[(sb * 10 + u) * 64 + lane];                   \
            unsigned short o[10];                                           \
            _Pragma("unroll")                                               \
            for (int u = 0; u < 10; ++u) {                                  \
                m = beta * m + (double)(v[u] + bj);                         \
                bool sp = (m >= 1.0);                                       \
                o[u] = sp ? (unsigned short)0x3F80 : (unsigned short)0;     \
                m = sp ? 0.0 : m;                                           \
            }                                                               \
            _Pragma("unroll")                                               \
            for (int u = 0; u < 10; ++u)                                    \
                ((unsigned short*)S)[(size_t)(btt + sb * 10 + u) * stride + gid] = o[u]; \
        }                                                                   \
    }

    H_PREFETCH(segA, 0);
    for (int s = 0; s < nseg; s += 2) {
        asm volatile("s_waitcnt vmcnt(0)" ::: "memory");
        __builtin_amdgcn_sched_barrier(0);
        H_PREFETCH(segB, s + 1);
        __builtin_amdgcn_sched_barrier(0);
        H_PROC(segA, s);
        asm volatile("s_waitcnt vmcnt(0)" ::: "memory");
        __builtin_amdgcn_sched_barrier(0);
        if (s + 2 < nseg) H_PREFETCH(segA, s + 2);
        __builtin_amdgcn_sched_barrier(0);
        H_PROC(segB, s + 1);
    }
    mstate[gid] = m;
#undef H_PREFETCH
#undef H_PROC
}

__global__ __launch_bounds__(256) void k_scan_out(
    const float* __restrict__ I2, const float* __restrict__ bias,
    double* __restrict__ mstate, float* __restrict__ out,
    int Tc, int t0, double beta) {
    __shared__ __align__(16) float segA[SEGO * 256];
    __shared__ __align__(16) float segB[SEGO * 256];
    const int tid  = threadIdx.x;
    const int lane = tid & 63;
    const int wave = tid >> 6;
    const int k = tid & 15;
    const int b = tid >> 4;
    double m = mstate[tid];
    float bj = (k < N_OUT) ? bias[k] : 0.f;
    const int nseg = Tc / SEGO;

#define O_PREFETCH(SEGBUF, SIDX)                                            \
    {                                                                       \
        const float* src = I2 + (size_t)(SIDX) * SEGO * 256 + wave * 64 + lane; \
        _Pragma("unroll 8")                                                 \
        for (int rr = 0; rr < SEGO; ++rr)                                   \
            __builtin_amdgcn_global_load_lds(                               \
                ASG(src + (size_t)rr * 256),                                \
                ASL(&SEGBUF[rr * 256 + wave * 64]), 4, 0, 0);               \
    }

#define O_PROC(SEGBUF, SIDX)                                                \
    {                                                                       \
        const int btt = (SIDX) * SEGO;                                      \
        _Pragma("unroll")                                                   \
        for (int sb = 0; sb < SEGO / 8; ++sb) {                             \
            float v[8];                                                     \
            _Pragma("unroll")                                               \
            for (int u = 0; u < 8; ++u)                                     \
                v[u] = SEGBUF[(sb * 8 + u) * 256 + tid];                    \
            float o[8];                                                     \
            _Pragma("unroll")                                               \
            for (int u = 0; u < 8; ++u) {                                   \
                m = beta * m + (double)(v[u] + bj);                         \
                bool sp = (m >= 1.0);                                       \
                o[u] = sp ? 1.f : 0.f;                                      \
                m = sp ? 0.0 : m;                                           \
            }                                                               \
            if (k < N_OUT) {                                                \
                _Pragma("unroll")                                           \
                for (int u = 0; u < 8; ++u)                                 \
                    out[((size_t)(t0 + btt + sb * 8 + u) * NB + b) * N_OUT + k] = o[u]; \
            }                                                               \
        }                                                                   \
    }

    O_PREFETCH(segA, 0);
    for (int s = 0; s < nseg; s += 2) {
        asm volatile("s_waitcnt vmcnt(0)" ::: "memory");
        __builtin_amdgcn_sched_barrier(0);
        O_PREFETCH(segB, s + 1);
        __builtin_amdgcn_sched_barrier(0);
        O_PROC(segA, s);
        asm volatile("s_waitcnt vmcnt(0)" ::: "memory");
        __builtin_amdgcn_sched_barrier(0);
        if (s + 2 < nseg) O_PREFETCH(segA, s + 2);
        __builtin_amdgcn_sched_barrier(0);
        O_PROC(segB, s + 1);
    }
    mstate[tid] = m;
#undef O_PREFETCH
#undef O_PROC
}

// ---------------- host ----------------

extern "C" void kernel_launch(void* const* d_in, const int* in_sizes, int n_in,
                              void* d_out, int out_size, void* d_ws, size_t ws_size,
                              hipStream_t stream) {
    const float* in_sp = (const float*)d_in[0];
    const float* W0 = (const float*)d_in[1];
    const float* b0 = (const float*)d_in[2];
    const float* W1 = (const float*)d_in[3];
    const float* b1 = (const float*)d_in[4];
    const float* W2 = (const float*)d_in[5];
    const float* b2 = (const float*)d_in[6];
    float* out = (float*)d_out;

    char* p = (char*)d_ws;
    auto carve = [&](size_t bytes) -> void* {
        char* r = p; p += (bytes + 255) & ~(size_t)255; return (void*)r;
    };
    bf16* A_in = (bf16*)carve((size_t)T_STEPS * NB * N_IN * 2);
    bf16* BT0  = (bf16*)carve((size_t)NH * 2 * N_IN * 2);
    bf16* BT1  = (bf16*)carve((size_t)NH * 2 * NH * 2);
    bf16* BT2  = (bf16*)carve((size_t)128 * 2 * NH * 2);
    double* m0s = (double*)carve((size_t)NB * NH * 8);
    double* m1s = (double*)carve((size_t)NB * NH * 8);
    double* m2s = (double*)carve((size_t)NB * 16 * 8);
    size_t fixed = (size_t)(p - (char*)d_ws);

    // Tc | 4000, Tc % 400 == 0 (scan segs), Mc % 128 == 0
    const int tc_opts[3] = {2000, 800, 400};
    int Tc = 400;
    for (int i = 0; i < 3; ++i) {
        size_t Mc_ = (size_t)tc_opts[i] * NB;
        size_t need = fixed
            + ((Mc_ * NH * 4 + 255) & ~(size_t)255)
            + ((Mc_ * 16 * 4 + 255) & ~(size_t)255)
            + ((Mc_ * NH * 2 + 255) & ~(size_t)255);
        if (need <= ws_size) { Tc = tc_opts[i]; break; }
    }
    size_t Mc = (size_t)Tc * NB;
    float* IBUF  = (float*)carve(Mc * NH * 4);
    float* I2BUF = (float*)carve(Mc * 16 * 4);
    bf16*  S     = (bf16*)carve(Mc * NH * 2);

    const int use8 = (Mc % 256 == 0);     // layer-1 kernel choice
    const double beta = exp(-0.25 / 10.0);

    int nM = NB * NH;
    k_zero<<<(nM + 255) / 256, 256, 0, stream>>>(m0s, nM);
    k_zero<<<(nM + 255) / 256, 256, 0, stream>>>(m1s, nM);
    k_zero<<<1, 256, 0, stream>>>(m2s, NB * 16);

    int nIn = T_STEPS * NB * N_IN;
    k_cvt<<<(nIn + 255) / 256, 256, 0, stream>>>(in_sp, A_in, nIn);

    k_limbs<<<(NH * 2 * N_IN + 255) / 256, 256, 0, stream>>>(W0, BT0, N_IN, NH, NH, 1);
    k_limbs<<<(NH * 2 * NH + 255) / 256, 256, 0, stream>>>(W1, BT1, NH, NH, NH, use8 ? 0 : 1);
    k_limbs<<<(128 * 2 * NH + 255) / 256, 256, 0, stream>>>(W2, BT2, NH, N_OUT, 128, 1);

    const int C = T_STEPS / Tc;
    const int gx = (int)(Mc / 128);
    const int gx8 = (int)(Mc / 256);
    for (int c = 0; c < C; ++c) {
        int t0 = c * Tc;
        const bf16* Ain_c = A_in + (size_t)t0 * NB * N_IN;
        // layer 0 (128^2 kernel, interleaved limbs)
        k_gemm<<<gx * 8, 256, 0, stream>>>(Ain_c, BT0, IBUF, N_IN, 2 * N_IN, NH, gx);
        k_scan_hidden<<<(NB * NH) / 64, 64, 0, stream>>>(IBUF, b0, m0s, S, Tc, beta);
        // layer 1 (256^2 8-phase kernel when shape permits)
        if (use8)
            k_gemm8<<<gx8 * 4, 512, 0, stream>>>(S, BT1, IBUF, gx8);
        else
            k_gemm<<<gx * 8, 256, 0, stream>>>(S, BT1, IBUF, NH, 2 * NH, NH, gx);
        k_scan_hidden<<<(NB * NH) / 64, 64, 0, stream>>>(IBUF, b1, m1s, S, Tc, beta);
        // layer 2 (compact 16-col C)
        k_gemm<<<gx, 256, 0, stream>>>(S, BT2, I2BUF, NH, 2 * NH, 16, gx);
        k_scan_out<<<1, 256, 0, stream>>>(I2BUF, b2, m2s, out, Tc, t0, beta);
    }
}

// Round 9
// 953.895 us; speedup vs baseline: 1.0887x; 1.0323x over previous
//
#include <hip/hip_runtime.h>
#include <hip/hip_bf16.h>
#include <math.h>

// SNN forward: 64 -> 1024 -> 1024 -> 10, T=4000, B=16, LIF beta=exp(-0.025),
// thr=1, hard reset to 0, Dale clamp W>=0.
// Layer-phased: per time-chunk, GEMM (spikes @ W bf16-limbs, fp32 acc) ->
// LIF scan (fp64 membranes). Spikes as bf16 {0,1}.
// R9: counted vmcnt in both scans (T4): issue next segment's loads, then
// s_waitcnt vmcnt(SEG) so only the older segment must be resident -- the
// in-flight 50 loads hide under processing (was: full vmcnt(0) drain per
// segment, serializing issue->drain at 1 wave/CU).

#define T_STEPS 4000
#define NB 16
#define N_IN 64
#define NH 1024
#define N_OUT 10
#define SEGO 40           // scan_out segment rows; vmcnt(40) literal below
#define SEGH 50           // scan_hidden segment rows; vmcnt(50) literal below

typedef __attribute__((ext_vector_type(8))) short bf16x8;
typedef __attribute__((ext_vector_type(4))) float f32x4;
typedef __hip_bfloat16 bf16;

#define ASG(p) (const __attribute__((address_space(1))) void*)(p)
#define ASL(p) (__attribute__((address_space(3))) void*)(p)

// ---------------- small utility kernels ----------------

__global__ void k_zero(double* p, int n) {
    int i = blockIdx.x * 256 + threadIdx.x;
    if (i < n) p[i] = 0.0;
}

__global__ void k_cvt(const float* __restrict__ in, bf16* __restrict__ out, int n) {
    int i = blockIdx.x * 256 + threadIdx.x;
    if (i < n) out[i] = __float2bfloat16(in[i]);   // 0.0/1.0 -> exact
}

// Build BT[n][k2] (row-major [Npad x 2K]) from W [K x N] row-major.
// interleave=1: [hi64|lo64] alternating per source 64-block (for k_gemm's
//               A-tile-reuse addressing).
// interleave=0: plain [hi(0..K) | lo(0..K)] (for k_gemm8; A col = k2 & (K-1)).
__global__ void k_limbs(const float* __restrict__ W, bf16* __restrict__ BT,
                        int K, int N, int Npad, int interleave) {
    int idx = blockIdx.x * 256 + threadIdx.x;
    int total = Npad * 2 * K;
    if (idx >= total) return;
    int n  = idx / (2 * K);
    int k2 = idx - n * (2 * K);
    int k, lo;
    if (interleave) {
        int kt2 = k2 >> 6, kk = k2 & 63;
        k = ((kt2 >> 1) << 6) + kk;
        lo = kt2 & 1;
    } else {
        lo = (k2 >= K);
        k = lo ? (k2 - K) : k2;
    }
    float v = 0.f;
    if (n < N) {
        float w = fmaxf(W[(size_t)k * N + n], 0.f);      // Dale's law clamp
        float hi = __bfloat162float(__float2bfloat16(w));
        v = lo ? (w - hi) : w;
    }
    BT[idx] = __float2bfloat16(v);
}

// ---------------- 128^2 2-phase GEMM (layers 0 and 2) ----------------
// BT interleaved: k-iteration kt uses A k-tile (kt>>1).

__global__ __launch_bounds__(256) void k_gemm(
    const bf16* __restrict__ A, const bf16* __restrict__ BT,
    float* __restrict__ C, int KA, int K2, int ldc, int gx) {
    const int nwg = gridDim.x;
    const int wg  = blockIdx.x;
    const int q = nwg >> 3, r = nwg & 7;
    const int xcd = wg & 7, idx0 = wg >> 3;
    const int swz = (xcd < r ? xcd * (q + 1) : r * (q + 1) + (xcd - r) * q) + idx0;
    const int gy = nwg / gx;
    const int n0 = (swz % gy) * 128;      // n-major within XCD chunk
    const int m0 = (swz / gy) * 128;
    __shared__ __align__(16) short Alds[128 * 64];
    __shared__ __align__(16) short Blds[128 * 64];
    const int tid  = threadIdx.x;
    const int lane = tid & 63;
    const int wave = tid >> 6;
    const int wbase = wave * 64;
    const int wm = (wave >> 1) * 64;
    const int wn = (wave & 1) * 64;
    const int r16 = lane & 15;
    const int kg  = lane >> 4;
    f32x4 acc[4][4] = {};
    const int nkt = K2 >> 6;
    for (int kt = 0; kt < nkt; ++kt) {
        const int kB0 = kt << 6;
        const int kA0 = (kt >> 1) << 6;
        __syncthreads();
#pragma unroll
        for (int rr = 0; rr < 4; ++rr) {
            int idx = rr * 256 + wbase + lane;
            int row = idx >> 3;
            int c8  = (idx & 7) << 3;
            if ((kt & 1) == 0)
                __builtin_amdgcn_global_load_lds(
                    ASG(&A[(size_t)(m0 + row) * KA + ((kA0 + c8) & (KA - 1))]),
                    ASL(&Alds[(rr * 256 + wbase) * 8]), 16, 0, 0);
            __builtin_amdgcn_global_load_lds(
                ASG(&BT[(size_t)(n0 + row) * K2 + kB0 + c8]),
                ASL(&Blds[(rr * 256 + wbase) * 8]), 16, 0, 0);
        }
        __syncthreads();
#pragma unroll
        for (int kk = 0; kk < 2; ++kk) {
            bf16x8 af[4], bfr[4];
#pragma unroll
            for (int i = 0; i < 4; ++i) {
                af[i]  = *(const bf16x8*)&Alds[(wm + i * 16 + r16) * 64 + kk * 32 + kg * 8];
                bfr[i] = *(const bf16x8*)&Blds[(wn + i * 16 + r16) * 64 + kk * 32 + kg * 8];
            }
#pragma unroll
            for (int mi = 0; mi < 4; ++mi)
#pragma unroll
                for (int ni = 0; ni < 4; ++ni)
                    acc[mi][ni] = __builtin_amdgcn_mfma_f32_16x16x32_bf16(
                        af[mi], bfr[ni], acc[mi][ni], 0, 0, 0);
        }
    }
#pragma unroll
    for (int mi = 0; mi < 4; ++mi)
#pragma unroll
        for (int ni = 0; ni < 4; ++ni) {
            int col = n0 + wn + ni * 16 + r16;
            if (col < ldc) {
#pragma unroll
                for (int rr = 0; rr < 4; ++rr) {
                    int row = m0 + wm + mi * 16 + kg * 4 + rr;
                    C[(size_t)row * ldc + col] = acc[mi][ni][rr];
                }
            }
        }
}

// ---------------- 256^2 8-phase GEMM (layer 1) ----------------
// Fixed shape: KA=1024, K2=2048, N=1024, ldc=1024. M multiple of 256.
// BT plain [hi|lo]; A col = k & 1023.
// LDS: 2 buf x {A,B} x 2 half-tiles x 16KB = 128 KB. Half-tile = 128x64 bf16,
// subtiled 16x32 (1024B), st_16x32 swizzle: byte ^= ((byte>>9)&1)<<5.
// Staging: linear LDS dest + pre-swizzled global source (rule #21).
// Stage ordering invariant (R8): a region is staged only in a phase after all
// ds_reads of it have drained past a barrier (A at P3, B at P2).

__global__ __launch_bounds__(512) void k_gemm8(
    const bf16* __restrict__ A, const bf16* __restrict__ BT,
    float* __restrict__ C, int gx) {
    const int KA = 1024, K2 = 2048;
    const int kmask = KA - 1;
    const int nwg = gridDim.x;
    const int wg  = blockIdx.x;
    const int q = nwg >> 3, r = nwg & 7;
    const int xcd = wg & 7, idx0 = wg >> 3;
    const int swz = (xcd < r ? xcd * (q + 1) : r * (q + 1) + (xcd - r) * q) + idx0;
    const int gy = nwg / gx;              // 4
    const int n0 = (swz % gy) * 256;      // n-major within XCD chunk
    const int m0 = (swz / gy) * 256;

    __shared__ __align__(16) char LDS[131072];
    const int tid  = threadIdx.x;
    const int lane = tid & 63;
    const int wave = tid >> 6;
    const int wm = (wave >> 2) * 128;     // 0 / 128
    const int wn = (wave & 3) * 64;       // 0..192
    const int r16l = lane & 15;
    const int kg   = lane >> 4;
    const int hA   = wave >> 2;           // A half this wave reads
    const int hB   = (wave & 3) >> 1;     // B half this wave reads
    const int wn64 = wave & 1;            // 64-col sub-block within B half

    // per-lane swizzled fragment-read offset within a half-tile
    const int po = (r16l * 64 + kg * 16) ^ (((r16l >> 3) & 1) << 5);
    const char* bA[2] = { LDS + hA * 16384 + po,
                          LDS + 65536 + hA * 16384 + po };
    const char* bB[2] = { LDS + 32768 + hB * 16384 + po,
                          LDS + 98304 + hB * 16384 + po };
    const int bOff = wn64 * 8192;

    // staging: per-thread pre-swizzled (row, col) for the 2 rounds
    int s_row[2], s_col[2];
#pragma unroll
    for (int rr = 0; rr < 2; ++rr) {
        int d = (rr * 512 + tid) * 16;            // linear LDS dest byte
        int l = d ^ (((d >> 9) & 1) << 5);        // logical element byte
        int sub = l >> 10;
        int w = l & 1023;
        s_row[rr] = (sub >> 1) * 16 + (w >> 6);
        s_col[rr] = ((sub & 1) * 64 + (w & 63)) >> 1;
    }

#define HBASE(BUF, OP, HALF) ((((BUF) * 2 + (OP)) * 2 + (HALF)) * 16384)
#define STAGE_A(BUF, HALF, K0)                                              \
    {                                                                       \
        _Pragma("unroll")                                                   \
        for (int rr = 0; rr < 2; ++rr)                                      \
            __builtin_amdgcn_global_load_lds(                               \
                ASG(A + (size_t)(m0 + (HALF) * 128 + s_row[rr]) * KA        \
                    + (((K0) + s_col[rr]) & kmask)),                        \
                ASL(LDS + HBASE(BUF, 0, HALF) + (rr * 512 + wave * 64) * 16), \
                16, 0, 0);                                                  \
    }
#define STAGE_B(BUF, HALF, K0)                                              \
    {                                                                       \
        _Pragma("unroll")                                                   \
        for (int rr = 0; rr < 2; ++rr)                                      \
            __builtin_amdgcn_global_load_lds(                               \
                ASG(BT + (size_t)(n0 + (HALF) * 128 + s_row[rr]) * K2       \
                    + (K0) + s_col[rr]),                                    \
                ASL(LDS + HBASE(BUF, 1, HALF) + (rr * 512 + wave * 64) * 16), \
                16, 0, 0);                                                  \
    }

    f32x4 acc[8][4] = {};
    bf16x8 a[4][2], b[4][2];

#define MM(MIB, NIB)                                                        \
    {                                                                       \
        _Pragma("unroll")                                                   \
        for (int i = 0; i < 4; ++i)                                         \
            _Pragma("unroll")                                               \
            for (int j = 0; j < 2; ++j) {                                   \
                acc[(MIB) + i][(NIB) + j] =                                 \
                    __builtin_amdgcn_mfma_f32_16x16x32_bf16(                \
                        a[i][0], b[(NIB) + j][0], acc[(MIB) + i][(NIB) + j], 0, 0, 0); \
                acc[(MIB) + i][(NIB) + j] =                                 \
                    __builtin_amdgcn_mfma_f32_16x16x32_bf16(                \
                        a[i][1], b[(NIB) + j][1], acc[(MIB) + i][(NIB) + j], 0, 0, 0); \
            }                                                               \
    }

#define PH_SYNC()                                                           \
    __builtin_amdgcn_s_barrier();                                           \
    asm volatile("s_waitcnt lgkmcnt(0)" ::: "memory");                      \
    __builtin_amdgcn_sched_barrier(0);

#define KTILE(BUF, SK)                                                      \
    {                                                                       \
        /* P0: ds a[0-3] (8) + b[0-1] (4); no stage */                      \
        _Pragma("unroll")                                                   \
        for (int i = 0; i < 4; ++i) {                                       \
            a[i][0] = *(const bf16x8*)(bA[BUF] + i * 2048);                 \
            a[i][1] = *(const bf16x8*)(bA[BUF] + i * 2048 + 1024);          \
        }                                                                   \
        _Pragma("unroll")                                                   \
        for (int j = 0; j < 2; ++j) {                                       \
            b[j][0] = *(const bf16x8*)(bB[BUF] + bOff + j * 2048);          \
            b[j][1] = *(const bf16x8*)(bB[BUF] + bOff + j * 2048 + 1024);   \
        }                                                                   \
        PH_SYNC();                                                          \
        __builtin_amdgcn_s_setprio(1);                                      \
        MM(0, 0);                                                           \
        __builtin_amdgcn_s_setprio(0);                                      \
        __builtin_amdgcn_s_barrier();                                       \
        /* P1: ds b[2-3] (4); no stage */                                   \
        _Pragma("unroll")                                                   \
        for (int j = 0; j < 2; ++j) {                                       \
            b[2 + j][0] = *(const bf16x8*)(bB[BUF] + bOff + (2 + j) * 2048); \
            b[2 + j][1] = *(const bf16x8*)(bB[BUF] + bOff + (2 + j) * 2048 + 1024); \
        }                                                                   \
        PH_SYNC();                                                          \
        __builtin_amdgcn_s_setprio(1);                                      \
        MM(0, 2);                                                           \
        __builtin_amdgcn_s_setprio(0);                                      \
        __builtin_amdgcn_s_barrier();                                       \
        /* P2: ds a[4-7] (8); stage B-h0+B-h1 (B reads drained at P1) */    \
        _Pragma("unroll")                                                   \
        for (int i = 0; i < 4; ++i) {                                       \
            a[i][0] = *(const bf16x8*)(bA[BUF] + (4 + i) * 2048);           \
            a[i][1] = *(const bf16x8*)(bA[BUF] + (4 + i) * 2048 + 1024);    \
        }                                                                   \
        STAGE_B(BUF, 0, SK);                                                \
        STAGE_B(BUF, 1, SK);                                                \
        PH_SYNC();                                                          \
        __builtin_amdgcn_s_setprio(1);                                      \
        MM(4, 0);                                                           \
        __builtin_amdgcn_s_setprio(0);                                      \
        __builtin_amdgcn_s_barrier();                                       \
        /* P3: stage A-h0+A-h1 (A reads drained at P2); vmcnt(8) */         \
        STAGE_A(BUF, 0, SK);                                                \
        STAGE_A(BUF, 1, SK);                                                \
        PH_SYNC();                                                          \
        __builtin_amdgcn_s_setprio(1);                                      \
        MM(4, 2);                                                           \
        __builtin_amdgcn_s_setprio(0);                                      \
        asm volatile("s_waitcnt vmcnt(8)" ::: "memory");                    \
        __builtin_amdgcn_sched_barrier(0);                                  \
        __builtin_amdgcn_s_barrier();                                       \
    }

    // prologue: stage tiles 0 (buf0) and 1 (buf1); wait tile0 collectively
    STAGE_A(0, 0, 0);  STAGE_A(0, 1, 0);  STAGE_B(0, 0, 0);  STAGE_B(0, 1, 0);
    STAGE_A(1, 0, 64); STAGE_A(1, 1, 64); STAGE_B(1, 0, 64); STAGE_B(1, 1, 64);
    asm volatile("s_waitcnt vmcnt(8)" ::: "memory");
    __builtin_amdgcn_sched_barrier(0);
    __builtin_amdgcn_s_barrier();

    for (int it = 0; it < 16; ++it) {
        const int k0  = it * 128;
        const int ksA = (k0 + 128) & (K2 - 1);   // buf0's next tile (wraps to dummy at tail)
        const int ksB = (k0 + 192) & (K2 - 1);   // buf1's next tile
        KTILE(0, ksA);
        KTILE(1, ksB);
    }
    asm volatile("s_waitcnt vmcnt(0)" ::: "memory");
    __builtin_amdgcn_sched_barrier(0);

    // epilogue: D row = kg*4 + rr, col = r16l
#pragma unroll
    for (int mi = 0; mi < 8; ++mi)
#pragma unroll
        for (int ni = 0; ni < 4; ++ni)
#pragma unroll
            for (int rr = 0; rr < 4; ++rr) {
                int row = m0 + wm + mi * 16 + kg * 4 + rr;
                int col = n0 + wn + ni * 16 + r16l;
                C[(size_t)row * 1024 + col] = acc[mi][ni][rr];
            }
#undef KTILE
#undef PH_SYNC
#undef MM
#undef STAGE_A
#undef STAGE_B
#undef HBASE
}

// ---------------- LIF scan kernels (fp64 membranes) ----------------
// Counted-vmcnt double buffer (R9): issue next segment's loads FIRST, then
// s_waitcnt vmcnt(SEG) -- only ops older than the newest SEG must complete,
// i.e. the previous segment. Next segment's loads stay in flight under PROC.

__global__ __launch_bounds__(64) void k_scan_hidden(
    const float* __restrict__ I, const float* __restrict__ bias,
    double* __restrict__ mstate, bf16* __restrict__ S, int Tc, double beta) {
    __shared__ __align__(16) float segA[SEGH * 64];
    __shared__ __align__(16) float segB[SEGH * 64];
    const int lane = threadIdx.x;
    const int gid  = blockIdx.x * 64 + lane;
    const int j = gid & (NH - 1);
    double m = mstate[gid];
    const float bj = bias[j];
    const size_t stride = (size_t)NB * NH;
    const int nseg = Tc / SEGH;                  // even (Tc % 400 == 0)

#define H_PREFETCH(SEGBUF, SIDX)                                            \
    {                                                                       \
        const float* src = I + (size_t)(SIDX) * SEGH * stride + gid;        \
        _Pragma("unroll")                                                   \
        for (int rr = 0; rr < SEGH; ++rr)                                   \
            __builtin_amdgcn_global_load_lds(                               \
                ASG(src + (size_t)rr * stride),                             \
                ASL(&SEGBUF[rr * 64]), 4, 0, 0);                            \
    }

#define H_PROC(SEGBUF, SIDX)                                                \
    {                                                                       \
        const int btt = (SIDX) * SEGH;                                      \
        _Pragma("unroll")                                                   \
        for (int sb = 0; sb < SEGH / 10; ++sb) {                            \
            float v[10];                                                    \
            _Pragma("unroll")                                               \
            for (int u = 0; u < 10; ++u)                                    \
                v[u] = SEGBUF[(sb * 10 + u) * 64 + lane];                   \
            unsigned short o[10];                                           \
            _Pragma("unroll")                                               \
            for (int u = 0; u < 10; ++u) {                                  \
                m = beta * m + (double)(v[u] + bj);                         \
                bool sp = (m >= 1.0);                                       \
                o[u] = sp ? (unsigned short)0x3F80 : (unsigned short)0;     \
                m = sp ? 0.0 : m;                                           \
            }                                                               \
            _Pragma("unroll")                                               \
            for (int u = 0; u < 10; ++u)                                    \
                ((unsigned short*)S)[(size_t)(btt + sb * 10 + u) * stride + gid] = o[u]; \
        }                                                                   \
    }

    H_PREFETCH(segA, 0);
    for (int s = 0; s < nseg; s += 2) {
        H_PREFETCH(segB, s + 1);                         // s+1 < nseg (even nseg)
        asm volatile("s_waitcnt vmcnt(50)" ::: "memory"); // == SEGH: segA resident
        __builtin_amdgcn_sched_barrier(0);
        H_PROC(segA, s);
        if (s + 2 < nseg) {
            H_PREFETCH(segA, s + 2);
            asm volatile("s_waitcnt vmcnt(50)" ::: "memory"); // segB resident
        } else {
            asm volatile("s_waitcnt vmcnt(0)" ::: "memory");
        }
        __builtin_amdgcn_sched_barrier(0);
        H_PROC(segB, s + 1);
    }
    mstate[gid] = m;
#undef H_PREFETCH
#undef H_PROC
}

__global__ __launch_bounds__(256) void k_scan_out(
    const float* __restrict__ I2, const float* __restrict__ bias,
    double* __restrict__ mstate, float* __restrict__ out,
    int Tc, int t0, double beta) {
    __shared__ __align__(16) float segA[SEGO * 256];
    __shared__ __align__(16) float segB[SEGO * 256];
    const int tid  = threadIdx.x;
    const int lane = tid & 63;
    const int wave = tid >> 6;
    const int k = tid & 15;
    const int b = tid >> 4;
    double m = mstate[tid];
    float bj = (k < N_OUT) ? bias[k] : 0.f;
    const int nseg = Tc / SEGO;                  // even (Tc % 400 == 0)

#define O_PREFETCH(SEGBUF, SIDX)                                            \
    {                                                                       \
        const float* src = I2 + (size_t)(SIDX) * SEGO * 256 + wave * 64 + lane; \
        _Pragma("unroll 8")                                                 \
        for (int rr = 0; rr < SEGO; ++rr)                                   \
            __builtin_amdgcn_global_load_lds(                               \
                ASG(src + (size_t)rr * 256),                                \
                ASL(&SEGBUF[rr * 256 + wave * 64]), 4, 0, 0);               \
    }

#define O_PROC(SEGBUF, SIDX)                                                \
    {                                                                       \
        const int btt = (SIDX) * SEGO;                                      \
        _Pragma("unroll")                                                   \
        for (int sb = 0; sb < SEGO / 8; ++sb) {                             \
            float v[8];                                                     \
            _Pragma("unroll")                                               \
            for (int u = 0; u < 8; ++u)                                     \
                v[u] = SEGBUF[(sb * 8 + u) * 256 + tid];                    \
            float o[8];                                                     \
            _Pragma("unroll")                                               \
            for (int u = 0; u < 8; ++u) {                                   \
                m = beta * m + (double)(v[u] + bj);                         \
                bool sp = (m >= 1.0);                                       \
                o[u] = sp ? 1.f : 0.f;                                      \
                m = sp ? 0.0 : m;                                           \
            }                                                               \
            if (k < N_OUT) {                                                \
                _Pragma("unroll")                                           \
                for (int u = 0; u < 8; ++u)                                 \
                    out[((size_t)(t0 + btt + sb * 8 + u) * NB + b) * N_OUT + k] = o[u]; \
            }                                                               \
        }                                                                   \
    }

    O_PREFETCH(segA, 0);
    for (int s = 0; s < nseg; s += 2) {
        O_PREFETCH(segB, s + 1);                         // s+1 < nseg (even nseg)
        asm volatile("s_waitcnt vmcnt(40)" ::: "memory"); // == SEGO: segA resident
        __builtin_amdgcn_sched_barrier(0);
        O_PROC(segA, s);
        if (s + 2 < nseg) {
            O_PREFETCH(segA, s + 2);
            asm volatile("s_waitcnt vmcnt(40)" ::: "memory"); // segB resident
        } else {
            asm volatile("s_waitcnt vmcnt(0)" ::: "memory");
        }
        __builtin_amdgcn_sched_barrier(0);
        O_PROC(segB, s + 1);
    }
    mstate[tid] = m;
#undef O_PREFETCH
#undef O_PROC
}

// ---------------- host ----------------

extern "C" void kernel_launch(void* const* d_in, const int* in_sizes, int n_in,
                              void* d_out, int out_size, void* d_ws, size_t ws_size,
                              hipStream_t stream) {
    const float* in_sp = (const float*)d_in[0];
    const float* W0 = (const float*)d_in[1];
    const float* b0 = (const float*)d_in[2];
    const float* W1 = (const float*)d_in[3];
    const float* b1 = (const float*)d_in[4];
    const float* W2 = (const float*)d_in[5];
    const float* b2 = (const float*)d_in[6];
    float* out = (float*)d_out;

    char* p = (char*)d_ws;
    auto carve = [&](size_t bytes) -> void* {
        char* r = p; p += (bytes + 255) & ~(size_t)255; return (void*)r;
    };
    bf16* A_in = (bf16*)carve((size_t)T_STEPS * NB * N_IN * 2);
    bf16* BT0  = (bf16*)carve((size_t)NH * 2 * N_IN * 2);
    bf16* BT1  = (bf16*)carve((size_t)NH * 2 * NH * 2);
    bf16* BT2  = (bf16*)carve((size_t)128 * 2 * NH * 2);
    double* m0s = (double*)carve((size_t)NB * NH * 8);
    double* m1s = (double*)carve((size_t)NB * NH * 8);
    double* m2s = (double*)carve((size_t)NB * 16 * 8);
    size_t fixed = (size_t)(p - (char*)d_ws);

    // Tc | 4000, Tc % 400 == 0 (scan segs even), Mc % 128 == 0
    const int tc_opts[3] = {2000, 800, 400};
    int Tc = 400;
    for (int i = 0; i < 3; ++i) {
        size_t Mc_ = (size_t)tc_opts[i] * NB;
        size_t need = fixed
            + ((Mc_ * NH * 4 + 255) & ~(size_t)255)
            + ((Mc_ * 16 * 4 + 255) & ~(size_t)255)
            + ((Mc_ * NH * 2 + 255) & ~(size_t)255);
        if (need <= ws_size) { Tc = tc_opts[i]; break; }
    }
    size_t Mc = (size_t)Tc * NB;
    float* IBUF  = (float*)carve(Mc * NH * 4);
    float* I2BUF = (float*)carve(Mc * 16 * 4);
    bf16*  S     = (bf16*)carve(Mc * NH * 2);

    const int use8 = (Mc % 256 == 0);     // layer-1 kernel choice
    const double beta = exp(-0.25 / 10.0);

    // m0s/m1s/m2s are contiguous carves (each a multiple of 256B): one zero.
    int nM = NB * NH * 2 + NB * 16;
    k_zero<<<(nM + 255) / 256, 256, 0, stream>>>(m0s, nM);

    int nIn = T_STEPS * NB * N_IN;
    k_cvt<<<(nIn + 255) / 256, 256, 0, stream>>>(in_sp, A_in, nIn);

    k_limbs<<<(NH * 2 * N_IN + 255) / 256, 256, 0, stream>>>(W0, BT0, N_IN, NH, NH, 1);
    k_limbs<<<(NH * 2 * NH + 255) / 256, 256, 0, stream>>>(W1, BT1, NH, NH, NH, use8 ? 0 : 1);
    k_limbs<<<(128 * 2 * NH + 255) / 256, 256, 0, stream>>>(W2, BT2, NH, N_OUT, 128, 1);

    const int C = T_STEPS / Tc;
    const int gx = (int)(Mc / 128);
    const int gx8 = (int)(Mc / 256);
    for (int c = 0; c < C; ++c) {
        int t0 = c * Tc;
        const bf16* Ain_c = A_in + (size_t)t0 * NB * N_IN;
        // layer 0 (128^2 kernel, interleaved limbs)
        k_gemm<<<gx * 8, 256, 0, stream>>>(Ain_c, BT0, IBUF, N_IN, 2 * N_IN, NH, gx);
        k_scan_hidden<<<(NB * NH) / 64, 64, 0, stream>>>(IBUF, b0, m0s, S, Tc, beta);
        // layer 1 (256^2 8-phase kernel when shape permits)
        if (use8)
            k_gemm8<<<gx8 * 4, 512, 0, stream>>>(S, BT1, IBUF, gx8);
        else
            k_gemm<<<gx * 8, 256, 0, stream>>>(S, BT1, IBUF, NH, 2 * NH, NH, gx);
        k_scan_hidden<<<(NB * NH) / 64, 64, 0, stream>>>(IBUF, b1, m1s, S, Tc, beta);
        // layer 2 (compact 16-col C)
        k_gemm<<<gx, 256, 0, stream>>>(S, BT2, I2BUF, NH, 2 * NH, 16, gx);
        k_scan_out<<<1, 256, 0, stream>>>(I2BUF, b2, m2s, out, Tc, t0, beta);
    }
}